// Round 6
// baseline (68.068 us; speedup 1.0000x reference)
//
#include <hip/hip_runtime.h>

#define NG 64
#define NT 8192
#define NE 64
#define Z_COEF 0.001f
#define A_COEF 0.001f

#define BLK 256                  // 4 waves
#define ITERS 4                  // 16 tokens per iter per wave
#define TPW 64                   // tokens per wave
#define TPB 256                  // tokens per block (4 waves * 64)
#define NBLK (NG * (NT / TPB))   // 2048 (32 blocks per group)

#define DPP_XOR1  0xB1           // quad_perm(1,0,3,2)  : lane ^ 1
#define DPP_XOR2  0x4E           // quad_perm(2,3,0,1)  : lane ^ 2
#define DPP_HMIRR 0x141          // row_half_mirror     : lane ^ 7 within 8
#define DPP_MIRR  0x140          // row_mirror          : lane ^ 15 within 16

template <int CTRL>
__device__ __forceinline__ float fdpp(float x) {
    return __int_as_float(__builtin_amdgcn_mov_dpp(__float_as_int(x), CTRL, 0xF, 0xF, true));
}
template <int CTRL>
__device__ __forceinline__ int idpp(int x) {
    return __builtin_amdgcn_mov_dpp(x, CTRL, 0xF, 0xF, true);
}

template <int CTRL>
__device__ __forceinline__ void bfly_maxidx(float& m, int& me) {
    const float om  = fdpp<CTRL>(m);
    const int   ome = idpp<CTRL>(me);
    const bool  u   = (om > m) || (om == m && ome < me);
    me = u ? ome : me;
    m  = fmaxf(m, om);
}

// ws layout (all written every launch, no zeroing needed):
//   float pps [NBLK][NE]   per-block prob sums
//   uint  pcnt[NBLK][NE]   per-block argmax counts
//   float pz  [NBLK]       per-block z partials

__global__ __launch_bounds__(BLK, 8) void router_main(
    const float* __restrict__ logits,
    float* __restrict__ pps,
    unsigned int* __restrict__ pcnt,
    float* __restrict__ pz)
{
    const int tid  = threadIdx.x;
    const int lane = tid & 63;
    const int wv   = tid >> 6;       // wave in block 0..3
    const int c    = lane & 15;      // expert chunk: experts 4c .. 4c+3

    const int g     = blockIdx.x >> 5;                  // 32 blocks per group
    const int tbase = (blockIdx.x & 31) * TPB + wv * TPW;

    // fully coalesced: per instruction k, lane l reads bytes [k*1024 + l*16)
    // of the wave's 4KB token chunk -> token 4k+(l>>4), experts [4*(l&15),+4)
    const float* p0 = logits + ((size_t)g * NT + tbase) * NE + lane * 4;

    __shared__ float        s_ps[NE];
    __shared__ unsigned int s_cnt[NE];
    __shared__ float        s_z;
    if (tid < NE) { s_ps[tid] = 0.f; s_cnt[tid] = 0u; }
    if (tid == 0) s_z = 0.f;
    __syncthreads();

    float accp[4] = {0.f, 0.f, 0.f, 0.f};
    float accz = 0.f;

    float4 cur[4], nxt[4];
#pragma unroll
    for (int k = 0; k < 4; ++k)
        cur[k] = *reinterpret_cast<const float4*>(p0 + k * 256);

    for (int it = 0; it < ITERS; ++it) {
        const int nit = (it + 1 < ITERS) ? (it + 1) : it;
        const float* pn = p0 + (size_t)nit * 1024;
#pragma unroll
        for (int k = 0; k < 4; ++k)
            nxt[k] = *reinterpret_cast<const float4*>(pn + k * 256);

#pragma unroll
        for (int k = 0; k < 4; ++k) {
            const float v0 = cur[k].x, v1 = cur[k].y, v2 = cur[k].z, v3 = cur[k].w;

            // local max + argmax over this lane's 4 experts (first idx on ties)
            float m = v0; int mi = 0;
            if (v1 > m) { m = v1; mi = 1; }
            if (v2 > m) { m = v2; mi = 2; }
            if (v3 > m) { m = v3; mi = 3; }
            int me = (c << 2) + mi;
            const float ml = m;

            // exps against LOCAL max (overlaps with the butterfly below)
            const float e0 = __expf(v0 - ml), e1 = __expf(v1 - ml);
            const float e2 = __expf(v2 - ml), e3 = __expf(v3 - ml);
            float s = (e0 + e1) + (e2 + e3);

            // 16-lane max/argmax butterfly, pure-VALU DPP
            bfly_maxidx<DPP_XOR1>(m, me);
            bfly_maxidx<DPP_XOR2>(m, me);
            bfly_maxidx<DPP_HMIRR>(m, me);
            bfly_maxidx<DPP_MIRR>(m, me);

            // rescale local sum to group max, 16-lane sum butterfly
            const float r = __expf(ml - m);
            s *= r;
            s += fdpp<DPP_XOR1>(s);
            s += fdpp<DPP_XOR2>(s);
            s += fdpp<DPP_HMIRR>(s);
            s += fdpp<DPP_MIRR>(s);

            const float wsc = r * __builtin_amdgcn_rcpf(s);
            accp[0] += e0 * wsc;
            accp[1] += e1 * wsc;
            accp[2] += e2 * wsc;
            accp[3] += e3 * wsc;

            if (c == 0) {                       // lanes 0,16,32,48: one token each
                const float lz = m + __logf(s);
                accz += lz * lz;
                atomicAdd(&s_cnt[me], 1u);
            }
        }
#pragma unroll
        for (int k = 0; k < 4; ++k) cur[k] = nxt[k];
    }

    // fold the 4 token-subgroups (lanes l, l^16, l^32 share an expert chunk)
#pragma unroll
    for (int j = 0; j < 4; ++j) {
        accp[j] += __shfl_xor(accp[j], 16);
        accp[j] += __shfl_xor(accp[j], 32);
    }
    if (lane < 16) {
#pragma unroll
        for (int j = 0; j < 4; ++j) atomicAdd(&s_ps[(c << 2) + j], accp[j]);
    }
    if (c == 0) atomicAdd(&s_z, accz);
    __syncthreads();

    // per-block partials: plain stores, every slot owned by exactly one block
    const int row = blockIdx.x;
    if (tid < NE) {
        pps [row * NE + tid] = s_ps[tid];
        pcnt[row * NE + tid] = s_cnt[tid];
    }
    if (tid == 0) pz[row] = s_z;
}

__global__ __launch_bounds__(1024) void router_final(
    const float* __restrict__ pps,
    const unsigned int* __restrict__ pcnt,
    const float* __restrict__ pz,
    const int* __restrict__ capp,
    float* __restrict__ out)
{
    const int tid  = threadIdx.x;
    const int lane = tid & 63;   // expert
    const int w    = tid >> 6;   // wave 0..15
    const unsigned int C = (unsigned int)(*capp);

    __shared__ float s_aux[16];
    __shared__ float s_zz[16];

    float acc = 0.f;
#pragma unroll
    for (int gi = 0; gi < NG / 16; ++gi) {
        const int g = w + gi * 16;
        unsigned int n = 0u;
        float        P = 0.f;
#pragma unroll
        for (int b = 0; b < 32; ++b) {
            const int row = g * 32 + b;          // coalesced: lane = expert
            n += pcnt[row * NE + lane];
            P += pps [row * NE + lane];
        }
        float ovf = (n > C) ? (float)(n - C) : 0.f;
#pragma unroll
        for (int off = 1; off <= 32; off <<= 1) ovf += __shfl_xor(ovf, off);
        float ce = fminf((float)n, (float)C);
        if (lane == 0) ce += ovf;    // dropped tokens argmax to expert 0
        acc += ce * P;
    }
#pragma unroll
    for (int off = 1; off <= 32; off <<= 1) acc += __shfl_xor(acc, off);
    if (lane == 0) s_aux[w] = acc;

    // z: 2048 partials, two per thread
    float zz = pz[tid] + pz[tid + 1024];
#pragma unroll
    for (int off = 1; off <= 32; off <<= 1) zz += __shfl_xor(zz, off);
    if (lane == 0) s_zz[w] = zz;
    __syncthreads();

    if (tid == 0) {
        float A = 0.f, Z = 0.f;
#pragma unroll
        for (int i = 0; i < 16; ++i) { A += s_aux[i]; Z += s_zz[i]; }
        // aux = sum_e c_e * P_e * NE / (NG * NT * NT)
        const float aux_loss = A * ((float)NE / ((float)NG * (float)NT * (float)NT));
        const float z_loss   = Z / ((float)NG * (float)NT);
        out[0] = Z_COEF * z_loss + A_COEF * aux_loss;
    }
}

extern "C" void kernel_launch(void* const* d_in, const int* in_sizes, int n_in,
                              void* d_out, int out_size, void* d_ws, size_t ws_size,
                              hipStream_t stream)
{
    const float* logits = (const float*)d_in[0];
    // d_in[1] = attention_mask (unused by the reference forward)
    const int* cap = (const int*)d_in[2];

    float*        pps  = (float*)d_ws;
    unsigned int* pcnt = (unsigned int*)((char*)d_ws + (size_t)NBLK * NE * 4);
    float*        pz   = (float*)((char*)d_ws + 2ull * NBLK * NE * 4);

    router_main<<<NBLK, BLK, 0, stream>>>(logits, pps, pcnt, pz);
    router_final<<<1, 1024, 0, stream>>>(pps, pcnt, pz, cap, (float*)d_out);
}

// Round 7
// 37.924 us; speedup vs baseline: 1.7949x; 1.7949x over previous
//
#include <hip/hip_runtime.h>

#define NG 64
#define NT 8192
#define NE 64
#define Z_COEF 0.001f
#define A_COEF 0.001f

#define BLK 512                  // 8 waves
#define ITERS 4                  // 16 tokens per iter per wave
#define TPW 64                   // tokens per wave
#define TPB 512                  // tokens per block (8 waves * 64)
#define NBLK (NG * (NT / TPB))   // 1024 (16 blocks per group)

#define DPP_XOR1  0xB1           // quad_perm(1,0,3,2)  : lane ^ 1
#define DPP_XOR2  0x4E           // quad_perm(2,3,0,1)  : lane ^ 2
#define DPP_HMIRR 0x141          // row_half_mirror     : lane ^ 7 within 8
#define DPP_MIRR  0x140          // row_mirror          : lane ^ 15 within 16

template <int CTRL>
__device__ __forceinline__ float fdpp(float x) {
    return __int_as_float(__builtin_amdgcn_mov_dpp(__float_as_int(x), CTRL, 0xF, 0xF, true));
}
template <int CTRL>
__device__ __forceinline__ int idpp(int x) {
    return __builtin_amdgcn_mov_dpp(x, CTRL, 0xF, 0xF, true);
}

template <int CTRL>
__device__ __forceinline__ void bfly_maxidx(float& m, int& me) {
    const float om  = fdpp<CTRL>(m);
    const int   ome = idpp<CTRL>(me);
    const bool  u   = (om > m) || (om == m && ome < me);
    me = u ? ome : me;
    m  = fmaxf(m, om);
}

// ws layout (all written every launch, no zeroing needed):
//   float pps [NBLK][NE]   per-block prob sums
//   uint  pcnt[NBLK][NE]   per-block argmax counts
//   float pz  [NBLK]       per-block z partials

__global__ __launch_bounds__(BLK) void router_main(
    const float* __restrict__ logits,
    float* __restrict__ pps,
    unsigned int* __restrict__ pcnt,
    float* __restrict__ pz)
{
    const int tid  = threadIdx.x;
    const int lane = tid & 63;
    const int wv   = tid >> 6;       // wave in block 0..7
    const int c    = lane & 15;      // expert chunk: experts 4c .. 4c+3

    const int g     = blockIdx.x >> 4;                  // 16 blocks per group
    const int tbase = (blockIdx.x & 15) * TPB + wv * TPW;

    // fully coalesced: per instruction k, lane l reads bytes [k*1024 + l*16)
    // of the wave's 4KB token chunk -> token 4k+(l>>4), experts [4*(l&15),+4)
    const float* p0 = logits + ((size_t)g * NT + tbase) * NE + lane * 4;

    __shared__ float        s_ps[NE];
    __shared__ unsigned int s_cnt[NE];
    __shared__ float        s_z;
    if (tid < NE) { s_ps[tid] = 0.f; s_cnt[tid] = 0u; }
    if (tid == 0) s_z = 0.f;
    __syncthreads();

    float accp[4] = {0.f, 0.f, 0.f, 0.f};
    float accz = 0.f;

    // no SW prefetch: rely on wave-level TLP (higher occupancy beats
    // double-buffering here; forcing it via launch_bounds spilled in R6)
    for (int it = 0; it < ITERS; ++it) {
        const float* pi = p0 + (size_t)it * 1024;
        float4 cur[4];
#pragma unroll
        for (int k = 0; k < 4; ++k)
            cur[k] = *reinterpret_cast<const float4*>(pi + k * 256);

#pragma unroll
        for (int k = 0; k < 4; ++k) {
            const float v0 = cur[k].x, v1 = cur[k].y, v2 = cur[k].z, v3 = cur[k].w;

            // local max + argmax over this lane's 4 experts (first idx on ties)
            float m = v0; int mi = 0;
            if (v1 > m) { m = v1; mi = 1; }
            if (v2 > m) { m = v2; mi = 2; }
            if (v3 > m) { m = v3; mi = 3; }
            int me = (c << 2) + mi;
            const float ml = m;

            // exps against LOCAL max (overlaps with the butterfly below)
            const float e0 = __expf(v0 - ml), e1 = __expf(v1 - ml);
            const float e2 = __expf(v2 - ml), e3 = __expf(v3 - ml);
            float s = (e0 + e1) + (e2 + e3);

            // 16-lane max/argmax butterfly, pure-VALU DPP
            bfly_maxidx<DPP_XOR1>(m, me);
            bfly_maxidx<DPP_XOR2>(m, me);
            bfly_maxidx<DPP_HMIRR>(m, me);
            bfly_maxidx<DPP_MIRR>(m, me);

            // rescale local sum to group max, 16-lane sum butterfly
            const float r = __expf(ml - m);
            s *= r;
            s += fdpp<DPP_XOR1>(s);
            s += fdpp<DPP_XOR2>(s);
            s += fdpp<DPP_HMIRR>(s);
            s += fdpp<DPP_MIRR>(s);

            const float wsc = r * __builtin_amdgcn_rcpf(s);
            accp[0] += e0 * wsc;
            accp[1] += e1 * wsc;
            accp[2] += e2 * wsc;
            accp[3] += e3 * wsc;

            if (c == 0) {                       // lanes 0,16,32,48: one token each
                const float lz = m + __logf(s);
                accz += lz * lz;
                atomicAdd(&s_cnt[me], 1u);
            }
        }
    }

    // fold the 4 token-subgroups (lanes l, l^16, l^32 share an expert chunk)
#pragma unroll
    for (int j = 0; j < 4; ++j) {
        accp[j] += __shfl_xor(accp[j], 16);
        accp[j] += __shfl_xor(accp[j], 32);
    }
    if (lane < 16) {
#pragma unroll
        for (int j = 0; j < 4; ++j) atomicAdd(&s_ps[(c << 2) + j], accp[j]);
    }
    if (c == 0) atomicAdd(&s_z, accz);
    __syncthreads();

    // per-block partials: plain stores, every slot owned by exactly one block
    const int row = blockIdx.x;
    if (tid < NE) {
        pps [row * NE + tid] = s_ps[tid];
        pcnt[row * NE + tid] = s_cnt[tid];
    }
    if (tid == 0) pz[row] = s_z;
}

__global__ __launch_bounds__(1024) void router_final(
    const float* __restrict__ pps,
    const unsigned int* __restrict__ pcnt,
    const float* __restrict__ pz,
    const int* __restrict__ capp,
    float* __restrict__ out)
{
    const int tid  = threadIdx.x;
    const int lane = tid & 63;   // expert
    const int w    = tid >> 6;   // wave 0..15
    const unsigned int C = (unsigned int)(*capp);

    __shared__ float s_aux[16];
    __shared__ float s_zz[16];

    float acc = 0.f;
#pragma unroll
    for (int gi = 0; gi < NG / 16; ++gi) {
        const int g = w + gi * 16;
        unsigned int n = 0u;
        float        P = 0.f;
#pragma unroll
        for (int b = 0; b < 16; ++b) {
            const int row = g * 16 + b;          // coalesced: lane = expert
            n += pcnt[row * NE + lane];
            P += pps [row * NE + lane];
        }
        float ovf = (n > C) ? (float)(n - C) : 0.f;
#pragma unroll
        for (int off = 1; off <= 32; off <<= 1) ovf += __shfl_xor(ovf, off);
        float ce = fminf((float)n, (float)C);
        if (lane == 0) ce += ovf;    // dropped tokens argmax to expert 0
        acc += ce * P;
    }
#pragma unroll
    for (int off = 1; off <= 32; off <<= 1) acc += __shfl_xor(acc, off);
    if (lane == 0) s_aux[w] = acc;

    // z: 1024 partials, one per main-block
    float zz = pz[tid];
#pragma unroll
    for (int off = 1; off <= 32; off <<= 1) zz += __shfl_xor(zz, off);
    if (lane == 0) s_zz[w] = zz;
    __syncthreads();

    if (tid == 0) {
        float A = 0.f, Z = 0.f;
#pragma unroll
        for (int i = 0; i < 16; ++i) { A += s_aux[i]; Z += s_zz[i]; }
        // aux = sum_e c_e * P_e * NE / (NG * NT * NT)
        const float aux_loss = A * ((float)NE / ((float)NG * (float)NT * (float)NT));
        const float z_loss   = Z / ((float)NG * (float)NT);
        out[0] = Z_COEF * z_loss + A_COEF * aux_loss;
    }
}

extern "C" void kernel_launch(void* const* d_in, const int* in_sizes, int n_in,
                              void* d_out, int out_size, void* d_ws, size_t ws_size,
                              hipStream_t stream)
{
    const float* logits = (const float*)d_in[0];
    // d_in[1] = attention_mask (unused by the reference forward)
    const int* cap = (const int*)d_in[2];

    float*        pps  = (float*)d_ws;
    unsigned int* pcnt = (unsigned int*)((char*)d_ws + (size_t)NBLK * NE * 4);
    float*        pz   = (float*)((char*)d_ws + 2ull * NBLK * NE * 4);

    router_main<<<NBLK, BLK, 0, stream>>>(logits, pps, pcnt, pz);
    router_final<<<1, 1024, 0, stream>>>(pps, pcnt, pz, cap, (float*)d_out);
}

// Round 8
// 36.973 us; speedup vs baseline: 1.8410x; 1.0257x over previous
//
#include <hip/hip_runtime.h>

#define NG 64
#define NT 8192
#define NE 64
#define Z_COEF 0.001f
#define A_COEF 0.001f

#define BLK 512                  // 8 waves
#define ITERS 4                  // 16 tokens per iter per wave
#define TPW 64                   // tokens per wave
#define TPB 512                  // tokens per block (8 waves * 64)
#define NBLK (NG * (NT / TPB))   // 1024 (16 blocks per group)

#define LOG2E 1.44269504088896340736f
#define LN2   0.69314718055994530942f
#define BIGIDX 1048576

#define DPP_XOR1  0xB1           // quad_perm(1,0,3,2)  : lane ^ 1
#define DPP_XOR2  0x4E           // quad_perm(2,3,0,1)  : lane ^ 2
#define DPP_HMIRR 0x141          // row_half_mirror     : lane ^ 7 within 8
#define DPP_MIRR  0x140          // row_mirror          : lane ^ 15 within 16

template <int CTRL>
__device__ __forceinline__ float fdpp(float x) {
    return __int_as_float(__builtin_amdgcn_mov_dpp(__float_as_int(x), CTRL, 0xF, 0xF, true));
}
template <int CTRL>
__device__ __forceinline__ int idpp(int x) {
    return __builtin_amdgcn_mov_dpp(x, CTRL, 0xF, 0xF, true);
}

// ws layout (all written every launch, no zeroing needed):
//   float pps [NBLK][NE]   per-block prob sums
//   uint  pcnt[NBLK][NE]   per-block argmax counts
//   float pz  [NBLK]       per-block z partials

__global__ __launch_bounds__(BLK) void router_main(
    const float* __restrict__ logits,
    float* __restrict__ pps,
    unsigned int* __restrict__ pcnt,
    float* __restrict__ pz)
{
    const int tid  = threadIdx.x;
    const int lane = tid & 63;
    const int wv   = tid >> 6;       // wave in block 0..7
    const int c    = lane & 15;      // expert chunk: experts 4c .. 4c+3
    const int cb   = c << 2;

    const int g     = blockIdx.x >> 4;                  // 16 blocks per group
    const int tbase = (blockIdx.x & 15) * TPB + wv * TPW;

    // fully coalesced: per instruction k, lane l reads bytes [k*1024 + l*16)
    // of the wave's 4KB token chunk -> token 4k+(l>>4), experts [4*(l&15),+4)
    const float* p0 = logits + ((size_t)g * NT + tbase) * NE + lane * 4;

    __shared__ float        s_ps[NE];
    __shared__ unsigned int s_cnt[NE];
    __shared__ float        s_z;
    if (tid < NE) { s_ps[tid] = 0.f; s_cnt[tid] = 0u; }
    if (tid == 0) s_z = 0.f;
    __syncthreads();

    float accp[4] = {0.f, 0.f, 0.f, 0.f};
    float accz = 0.f;

    for (int it = 0; it < ITERS; ++it) {
        const float* pi = p0 + (size_t)it * 1024;
        float4 cur[4];
#pragma unroll
        for (int k = 0; k < 4; ++k)
            cur[k] = *reinterpret_cast<const float4*>(pi + k * 256);

#pragma unroll
        for (int k = 0; k < 4; ++k) {
            const float v0 = cur[k].x, v1 = cur[k].y, v2 = cur[k].z, v3 = cur[k].w;

            // group max: local max3 chain + 4 DPP-fusable fmax stages
            float m = fmaxf(fmaxf(v0, v1), fmaxf(v2, v3));
            m = fmaxf(m, fdpp<DPP_XOR1>(m));
            m = fmaxf(m, fdpp<DPP_XOR2>(m));
            m = fmaxf(m, fdpp<DPP_HMIRR>(m));
            m = fmaxf(m, fdpp<DPP_MIRR>(m));

            // exps straight against group max (base-2, single v_exp each)
            const float e0 = exp2f((v0 - m) * LOG2E);
            const float e1 = exp2f((v1 - m) * LOG2E);
            const float e2 = exp2f((v2 - m) * LOG2E);
            const float e3 = exp2f((v3 - m) * LOG2E);
            float s = (e0 + e1) + (e2 + e3);

            // argmax = first index whose value equals the max (exact ref ties)
            int me = BIGIDX;
            if (v3 == m) me = cb + 3;
            if (v2 == m) me = cb + 2;
            if (v1 == m) me = cb + 1;
            if (v0 == m) me = cb + 0;
            // min-index butterfly (independent of the sum butterfly -> ILP)
            me = min(me, idpp<DPP_XOR1>(me));
            me = min(me, idpp<DPP_XOR2>(me));
            me = min(me, idpp<DPP_HMIRR>(me));
            me = min(me, idpp<DPP_MIRR>(me));

            // sum butterfly (DPP-fusable adds)
            s += fdpp<DPP_XOR1>(s);
            s += fdpp<DPP_XOR2>(s);
            s += fdpp<DPP_HMIRR>(s);
            s += fdpp<DPP_MIRR>(s);

            const float inv = __builtin_amdgcn_rcpf(s);
            accp[0] = fmaf(e0, inv, accp[0]);
            accp[1] = fmaf(e1, inv, accp[1]);
            accp[2] = fmaf(e2, inv, accp[2]);
            accp[3] = fmaf(e3, inv, accp[3]);

            // z-loss: all 16 lanes of a token hold identical (m, s);
            // accumulate unconditionally, divide by 16 at the block fold
            const float lz = fmaf(__log2f(s), LN2, m);
            accz = fmaf(lz, lz, accz);

            if (c == 0)                        // lanes 0,16,32,48: one token each
                atomicAdd(&s_cnt[me], 1u);
        }
    }

    // fold the 4 token-subgroups (lanes l, l^16, l^32 share an expert chunk)
#pragma unroll
    for (int j = 0; j < 4; ++j) {
        accp[j] += __shfl_xor(accp[j], 16);
        accp[j] += __shfl_xor(accp[j], 32);
    }
    if (lane < 16) {
#pragma unroll
        for (int j = 0; j < 4; ++j) atomicAdd(&s_ps[(c << 2) + j], accp[j]);
    }
    // z: every lane accumulated the token's lz^2 -> wave sum / 16
    accz += __shfl_xor(accz, 1);
    accz += __shfl_xor(accz, 2);
    accz += __shfl_xor(accz, 4);
    accz += __shfl_xor(accz, 8);
    accz += __shfl_xor(accz, 16);
    accz += __shfl_xor(accz, 32);
    if (lane == 0) atomicAdd(&s_z, accz * 0.0625f);
    __syncthreads();

    // per-block partials: plain stores, every slot owned by exactly one block
    const int row = blockIdx.x;
    if (tid < NE) {
        pps [row * NE + tid] = s_ps[tid];
        pcnt[row * NE + tid] = s_cnt[tid];
    }
    if (tid == 0) pz[row] = s_z;
}

__global__ __launch_bounds__(1024) void router_final(
    const float* __restrict__ pps,
    const unsigned int* __restrict__ pcnt,
    const float* __restrict__ pz,
    const int* __restrict__ capp,
    float* __restrict__ out)
{
    const int tid  = threadIdx.x;
    const int lane = tid & 63;   // expert
    const int w    = tid >> 6;   // wave 0..15
    const unsigned int C = (unsigned int)(*capp);

    __shared__ float s_aux[16];
    __shared__ float s_zz[16];

    float acc = 0.f;
#pragma unroll
    for (int gi = 0; gi < NG / 16; ++gi) {
        const int g = w + gi * 16;
        unsigned int n = 0u;
        float        P = 0.f;
#pragma unroll
        for (int b = 0; b < 16; ++b) {
            const int row = g * 16 + b;          // coalesced: lane = expert
            n += pcnt[row * NE + lane];
            P += pps [row * NE + lane];
        }
        float ovf = (n > C) ? (float)(n - C) : 0.f;
#pragma unroll
        for (int off = 1; off <= 32; off <<= 1) ovf += __shfl_xor(ovf, off);
        float ce = fminf((float)n, (float)C);
        if (lane == 0) ce += ovf;    // dropped tokens argmax to expert 0
        acc += ce * P;
    }
#pragma unroll
    for (int off = 1; off <= 32; off <<= 1) acc += __shfl_xor(acc, off);
    if (lane == 0) s_aux[w] = acc;

    // z: 1024 partials, one per main-block
    float zz = pz[tid];
#pragma unroll
    for (int off = 1; off <= 32; off <<= 1) zz += __shfl_xor(zz, off);
    if (lane == 0) s_zz[w] = zz;
    __syncthreads();

    if (tid == 0) {
        float A = 0.f, Z = 0.f;
#pragma unroll
        for (int i = 0; i < 16; ++i) { A += s_aux[i]; Z += s_zz[i]; }
        // aux = sum_e c_e * P_e * NE / (NG * NT * NT)
        const float aux_loss = A * ((float)NE / ((float)NG * (float)NT * (float)NT));
        const float z_loss   = Z / ((float)NG * (float)NT);
        out[0] = Z_COEF * z_loss + A_COEF * aux_loss;
    }
}

extern "C" void kernel_launch(void* const* d_in, const int* in_sizes, int n_in,
                              void* d_out, int out_size, void* d_ws, size_t ws_size,
                              hipStream_t stream)
{
    const float* logits = (const float*)d_in[0];
    // d_in[1] = attention_mask (unused by the reference forward)
    const int* cap = (const int*)d_in[2];

    float*        pps  = (float*)d_ws;
    unsigned int* pcnt = (unsigned int*)((char*)d_ws + (size_t)NBLK * NE * 4);
    float*        pz   = (float*)((char*)d_ws + 2ull * NBLK * NE * 4);

    router_main<<<NBLK, BLK, 0, stream>>>(logits, pps, pcnt, pz);
    router_final<<<1, 1024, 0, stream>>>(pps, pcnt, pz, cap, (float*)d_out);
}